// Round 8
// baseline (185.131 us; speedup 1.0000x reference)
//
#include <hip/hip_runtime.h>
#include <hip/hip_bf16.h>
#include <stdint.h>

#define N_BATCH 4096
#define D_DIM   1024
#define M_ROWS  8192                     // 2N
#define TINV    2.0f                     // 1/temperature
// acc = sum q(16 z_r) q(16 z_c) = 256*sim ; exp2(acc * log2(e)/(256 t))
#define EXP_SCALE_Q (2.8853900817779268f / 256.0f)
#define LN2 0.6931471805599453f
#define NB 64                            // 8192/128 tiles per dim
#define NTRI 2080                        // NB*(NB+1)/2 upper-tri tiles
#define NKT2 16                          // K steps of 64 (K=1024)

typedef float f32x4 __attribute__((ext_vector_type(4)));

__device__ __forceinline__ void load_lds16(const void* g, void* l) {
    __builtin_amdgcn_global_load_lds(
        (const __attribute__((address_space(1))) void*)g,
        (__attribute__((address_space(3))) void*)l, 16, 0, 0);
}

// ---- kernel 1: fused L2-normalize (fp8 e4m3 Z out, x16 scale) + positives --
// One wave per row-pair; wave-local shfl reduce; no LDS/syncthreads.
// Z stored as OCP e4m3 of (16 * z): values ~N(0,0.5), max ~2.7 << 448 --
// all in e4m3 normal range, RNE via v_cvt_pk_fp8_f32. Positives exact fp32.
__global__ __launch_bounds__(256) void norm_pos_kernel(
    const float* __restrict__ emb_i, const float* __restrict__ emb_j,
    uint8_t* __restrict__ z8, float* __restrict__ pos, float* __restrict__ denom)
{
    int w    = threadIdx.x >> 6;                 // wave 0..3
    int lane = threadIdx.x & 63;
    int row  = blockIdx.x * 4 + w;               // 0..4095 (grid = 1024)
    const float4* Ai = (const float4*)(emb_i + (size_t)row * D_DIM);
    const float4* Bj = (const float4*)(emb_j + (size_t)row * D_DIM);
    float4 a[4], b[4];
    #pragma unroll
    for (int j = 0; j < 4; ++j) {
        a[j] = Ai[lane + 64 * j];
        b[j] = Bj[lane + 64 * j];
    }
    float ssa = 0.f, ssb = 0.f, dot = 0.f;
    #pragma unroll
    for (int j = 0; j < 4; ++j) {
        ssa += a[j].x*a[j].x + a[j].y*a[j].y + a[j].z*a[j].z + a[j].w*a[j].w;
        ssb += b[j].x*b[j].x + b[j].y*b[j].y + b[j].z*b[j].z + b[j].w*b[j].w;
        dot += a[j].x*b[j].x + a[j].y*b[j].y + a[j].z*b[j].z + a[j].w*b[j].w;
    }
    #pragma unroll
    for (int m = 1; m < 64; m <<= 1) {
        ssa += __shfl_xor(ssa, m, 64);
        ssb += __shfl_xor(ssb, m, 64);
        dot += __shfl_xor(dot, m, 64);
    }
    float na = fmaxf(sqrtf(ssa), 1e-12f);
    float nb = fmaxf(sqrtf(ssb), 1e-12f);
    float sa = 16.0f / na, sb = 16.0f / nb;
    uint32_t* zr = (uint32_t*)(z8 + (size_t)row * D_DIM);
    uint32_t* zc = (uint32_t*)(z8 + (size_t)(row + N_BATCH) * D_DIM);
    #pragma unroll
    for (int j = 0; j < 4; ++j) {
        int ra = 0, rb = 0;
        ra = __builtin_amdgcn_cvt_pk_fp8_f32(a[j].x * sa, a[j].y * sa, ra, false);
        ra = __builtin_amdgcn_cvt_pk_fp8_f32(a[j].z * sa, a[j].w * sa, ra, true);
        rb = __builtin_amdgcn_cvt_pk_fp8_f32(b[j].x * sb, b[j].y * sb, rb, false);
        rb = __builtin_amdgcn_cvt_pk_fp8_f32(b[j].z * sb, b[j].w * sb, rb, true);
        zr[lane + 64 * j] = (uint32_t)ra;
        zc[lane + 64 * j] = (uint32_t)rb;
    }
    if (lane == 0) {
        pos[row] = dot / ((na * nb) / 256.0f) / 256.0f;  // == dot/(na*nb), keep fp32 exact
        denom[row] = 0.0f;
        denom[row + N_BATCH] = 0.0f;
    }
}

// ---- kernel 2: fused sim = Z Z^T -> exp -> masked row/col sums -----------
// Round-5 proven skeleton (3-ring, counted vmcnt(4), bare s_barrier,
// triangular grid + bijective XCD swizzle) ported to fp8 e4m3 at BK=64:
//  - per K-step LDS footprint identical (A 8KB + B 8KB per buf), 48 KiB ring
//    -> 3 blk/CU preserved; but K-steps HALVE (16) and HBM/LDS bytes halve.
//  - LDS layout [kh][row][32B] per operand: frag read = ds_read_b64 at
//    row*32 + quad*8; a wave's 64 lanes cover one contiguous 512B span ->
//    bank-uniform, NO swizzle needed (staging is plain linear DMA).
//  - frag mapping mirrors the verified bf16 16x16x32 pattern 1:1 (row=l15,
//    k-octet=quad, 8 elem/lane), elements 2B->1B; C/D layout dtype-indep.
// vmcnt ledger: 4 loads/thread/step; stage kt+2 during kt; boundary
// vmcnt(4) = kt+1 landed (FIFO), kt+2 in flight. vmcnt(0) only at tail.
__global__ __launch_bounds__(256, 3) void simexp_kernel(
    const uint8_t* __restrict__ Z, float* __restrict__ denom)
{
    // XCD swizzle then decode linear idx -> (by, bx) with bx >= by
    int orig = blockIdx.x;
    int idx  = (orig & 7) * (NTRI / 8) + (orig >> 3);
    int by = (int)((129.0f - sqrtf(16641.0f - 8.0f * (float)idx)) * 0.5f);
    if (by > NB - 1) by = NB - 1;
    if (by < 0) by = 0;
    int off = (by * (129 - by)) >> 1;           // tiles before row `by`
    while (off > idx)                 { --by; off = (by * (129 - by)) >> 1; }
    while (off + (NB - by) <= idx)    { off += NB - by; ++by; }
    int bx = by + (idx - off);

    int tile_m = by * 128, tile_n = bx * 128;

    // ring: [3][kh 0/1][128 rows * 32 B] per operand -> 24 KiB + 24 KiB
    __shared__ __align__(16) uint8_t shA[3][2 * 4096];
    __shared__ __align__(16) uint8_t shB[3][2 * 4096];

    int t    = threadIdx.x;
    int wv   = t >> 6;
    int lane = t & 63;
    int wave_m = (wv >> 1) * 64;
    int wave_n = (wv & 1) * 64;
    int quad = lane >> 4;
    int l15  = lane & 15;

    // staging: thread t covers (row = t>>1, 16B-half = t&1) of each kh plane;
    // LDS dest t*16 is linear; global src offset kh*32 + (t&1)*16 + kstep.
    const uint8_t* gA = Z + (size_t)(tile_m + (t >> 1)) * D_DIM + (t & 1) * 16;
    const uint8_t* gB = Z + (size_t)(tile_n + (t >> 1)) * D_DIM + (t & 1) * 16;

    f32x4 acc[4][4] = {};

    // prologue: stage K-steps 0 and 1 (8 loads/thread); step 0 landed
    #pragma unroll
    for (int pt = 0; pt < 2; ++pt) {
        #pragma unroll
        for (int kh = 0; kh < 2; ++kh) {
            load_lds16(gA + pt * 64 + kh * 32, &shA[pt][kh * 4096 + t * 16]);
            load_lds16(gB + pt * 64 + kh * 32, &shB[pt][kh * 4096 + t * 16]);
        }
    }
    asm volatile("s_waitcnt vmcnt(4)" ::: "memory");
    __builtin_amdgcn_sched_barrier(0);
    __builtin_amdgcn_s_barrier();

    int cur = 0;
    for (int kt = 0; kt < NKT2; ++kt) {
        int wrt = cur + 2; if (wrt >= 3) wrt -= 3;
        if (kt < NKT2 - 2) {             // stage K-step kt+2 into ring slot
            int k0 = (kt + 2) * 64;
            load_lds16(gA + k0,      &shA[wrt][t * 16]);
            load_lds16(gA + k0 + 32, &shA[wrt][4096 + t * 16]);
            load_lds16(gB + k0,      &shB[wrt][t * 16]);
            load_lds16(gB + k0 + 32, &shB[wrt][4096 + t * 16]);
        }
        const uint8_t* sA = shA[cur];
        const uint8_t* sB = shB[cur];
        #pragma unroll
        for (int kh = 0; kh < 2; ++kh) {
            long av[4], bv[4];
            #pragma unroll
            for (int f = 0; f < 4; ++f)
                av[f] = *(const long*)&sA[kh * 4096 + (wave_m + f * 16 + l15) * 32 + quad * 8];
            #pragma unroll
            for (int n = 0; n < 4; ++n)
                bv[n] = *(const long*)&sB[kh * 4096 + (wave_n + n * 16 + l15) * 32 + quad * 8];
            __builtin_amdgcn_s_setprio(1);
            #pragma unroll
            for (int fm = 0; fm < 4; ++fm)
                #pragma unroll
                for (int fn = 0; fn < 4; ++fn)
                    acc[fm][fn] = __builtin_amdgcn_mfma_f32_16x16x32_fp8_fp8(
                        av[fm], bv[fn], acc[fm][fn], 0, 0, 0);
            __builtin_amdgcn_s_setprio(0);
        }
        // boundary: kt+1 must be landed; kt+2's 4 loads may stay in flight
        if (kt < NKT2 - 2) asm volatile("s_waitcnt vmcnt(4)" ::: "memory");
        else               asm volatile("s_waitcnt vmcnt(0)" ::: "memory");
        __builtin_amdgcn_sched_barrier(0);
        __builtin_amdgcn_s_barrier();
        cur = (cur == 2) ? 0 : cur + 1;
    }

    // epilogue: e = exp2(acc * log2(e)/(256 t)) only where c>r; row/col sums
    int rbase = tile_m + wave_m + quad * 4;
    int cbase = tile_n + wave_n + l15;
    float colacc[4] = {0.f, 0.f, 0.f, 0.f};
    #pragma unroll
    for (int fm = 0; fm < 4; ++fm) {
        #pragma unroll
        for (int r = 0; r < 4; ++r) {
            int rg = rbase + fm * 16 + r;
            float rowacc = 0.f;
            #pragma unroll
            for (int fn = 0; fn < 4; ++fn) {
                int cg = cbase + fn * 16;
                float e = (cg > rg)
                    ? __builtin_amdgcn_exp2f(acc[fm][fn][r] * EXP_SCALE_Q)
                    : 0.f;
                rowacc += e;
                colacc[fn] += e;
            }
            rowacc += __shfl_xor(rowacc, 1, 64);
            rowacc += __shfl_xor(rowacc, 2, 64);
            rowacc += __shfl_xor(rowacc, 4, 64);
            rowacc += __shfl_xor(rowacc, 8, 64);
            if (l15 == 0) atomicAdd(&denom[rg], rowacc);
        }
    }
    #pragma unroll
    for (int fn = 0; fn < 4; ++fn) {
        float s = colacc[fn];
        s += __shfl_xor(s, 16, 64);
        s += __shfl_xor(s, 32, 64);
        if (quad == 0) atomicAdd(&denom[cbase + fn * 16], s);
    }
}

// ---- kernel 3: loss = [sum log(denom) - (2/t) sum pos] / 2N --------------
__global__ __launch_bounds__(1024) void finalize_kernel(
    const float* __restrict__ denom, const float* __restrict__ pos,
    float* __restrict__ out)
{
    float a1 = 0.f, a2 = 0.f;
    for (int r = threadIdx.x; r < M_ROWS; r += 1024)
        a1 += __builtin_amdgcn_logf(denom[r]) * LN2;   // v_log_f32 is log2
    for (int i = threadIdx.x; i < N_BATCH; i += 1024)
        a2 += pos[i];
    #pragma unroll
    for (int m = 1; m < 64; m <<= 1) {
        a1 += __shfl_xor(a1, m, 64);
        a2 += __shfl_xor(a2, m, 64);
    }
    __shared__ float r1[16], r2[16];
    int wv = threadIdx.x >> 6;
    if ((threadIdx.x & 63) == 0) { r1[wv] = a1; r2[wv] = a2; }
    __syncthreads();
    if (threadIdx.x == 0) {
        float s1 = 0.f, s2 = 0.f;
        #pragma unroll
        for (int w = 0; w < 16; ++w) { s1 += r1[w]; s2 += r2[w]; }
        out[0] = (s1 - 2.0f * TINV * s2) / (float)M_ROWS;
    }
}

extern "C" void kernel_launch(void* const* d_in, const int* in_sizes, int n_in,
                              void* d_out, int out_size, void* d_ws, size_t ws_size,
                              hipStream_t stream)
{
    const float* emb_i = (const float*)d_in[0];
    const float* emb_j = (const float*)d_in[1];
    float* out = (float*)d_out;

    char*    ws    = (char*)d_ws;
    uint8_t* z8    = (uint8_t*)ws;                                 // 8 MB
    float*   denom = (float*)(ws + (size_t)M_ROWS * D_DIM);        // 32 KB
    float*   pos   = denom + M_ROWS;                               // 16 KB

    hipLaunchKernelGGL(norm_pos_kernel, dim3(N_BATCH / 4), dim3(256), 0, stream,
                       emb_i, emb_j, z8, pos, denom);
    hipLaunchKernelGGL(simexp_kernel, dim3(NTRI), dim3(256), 0, stream,
                       z8, denom);
    hipLaunchKernelGGL(finalize_kernel, dim3(1), dim3(1024), 0, stream,
                       denom, pos, out);
}

// Round 9
// 167.624 us; speedup vs baseline: 1.1044x; 1.1044x over previous
//
#include <hip/hip_runtime.h>
#include <hip/hip_bf16.h>
#include <stdint.h>

#define N_BATCH 4096
#define D_DIM   1024
#define M_ROWS  8192                     // 2N
#define TINV    2.0f                     // 1/temperature
// acc = sum q(16 z_r) q(16 z_c) = 256*sim ; exp2(acc * log2(e)/(256 t))
#define EXP_SCALE_Q (2.8853900817779268f / 256.0f)
#define LN2 0.6931471805599453f
#define NB 64                            // 8192/128 tiles per dim
#define NTRI 2080                        // NB*(NB+1)/2 upper-tri tiles
#define NKT2 16                          // K steps of 64 (K=1024)

typedef float f32x4 __attribute__((ext_vector_type(4)));

__device__ __forceinline__ void load_lds16(const void* g, void* l) {
    __builtin_amdgcn_global_load_lds(
        (const __attribute__((address_space(1))) void*)g,
        (__attribute__((address_space(3))) void*)l, 16, 0, 0);
}

// ---- kernel 1: fused L2-normalize (fp8 e4m3 Z out, x16 scale) + positives --
// One wave per row-pair; wave-local shfl reduce; no LDS/syncthreads.
// Z stored as OCP e4m3 of (16 * z): values ~N(0,0.5), max ~2.7 << 448 --
// all in e4m3 normal range, RNE via v_cvt_pk_fp8_f32. Positives exact fp32.
__global__ __launch_bounds__(256) void norm_pos_kernel(
    const float* __restrict__ emb_i, const float* __restrict__ emb_j,
    uint8_t* __restrict__ z8, float* __restrict__ pos, float* __restrict__ denom)
{
    int w    = threadIdx.x >> 6;                 // wave 0..3
    int lane = threadIdx.x & 63;
    int row  = blockIdx.x * 4 + w;               // 0..4095 (grid = 1024)
    const float4* Ai = (const float4*)(emb_i + (size_t)row * D_DIM);
    const float4* Bj = (const float4*)(emb_j + (size_t)row * D_DIM);
    float4 a[4], b[4];
    #pragma unroll
    for (int j = 0; j < 4; ++j) {
        a[j] = Ai[lane + 64 * j];
        b[j] = Bj[lane + 64 * j];
    }
    float ssa = 0.f, ssb = 0.f, dot = 0.f;
    #pragma unroll
    for (int j = 0; j < 4; ++j) {
        ssa += a[j].x*a[j].x + a[j].y*a[j].y + a[j].z*a[j].z + a[j].w*a[j].w;
        ssb += b[j].x*b[j].x + b[j].y*b[j].y + b[j].z*b[j].z + b[j].w*b[j].w;
        dot += a[j].x*b[j].x + a[j].y*b[j].y + a[j].z*b[j].z + a[j].w*b[j].w;
    }
    #pragma unroll
    for (int m = 1; m < 64; m <<= 1) {
        ssa += __shfl_xor(ssa, m, 64);
        ssb += __shfl_xor(ssb, m, 64);
        dot += __shfl_xor(dot, m, 64);
    }
    float na = fmaxf(sqrtf(ssa), 1e-12f);
    float nb = fmaxf(sqrtf(ssb), 1e-12f);
    float sa = 16.0f / na, sb = 16.0f / nb;
    uint32_t* zr = (uint32_t*)(z8 + (size_t)row * D_DIM);
    uint32_t* zc = (uint32_t*)(z8 + (size_t)(row + N_BATCH) * D_DIM);
    #pragma unroll
    for (int j = 0; j < 4; ++j) {
        int ra = 0, rb = 0;
        ra = __builtin_amdgcn_cvt_pk_fp8_f32(a[j].x * sa, a[j].y * sa, ra, false);
        ra = __builtin_amdgcn_cvt_pk_fp8_f32(a[j].z * sa, a[j].w * sa, ra, true);
        rb = __builtin_amdgcn_cvt_pk_fp8_f32(b[j].x * sb, b[j].y * sb, rb, false);
        rb = __builtin_amdgcn_cvt_pk_fp8_f32(b[j].z * sb, b[j].w * sb, rb, true);
        zr[lane + 64 * j] = (uint32_t)ra;
        zc[lane + 64 * j] = (uint32_t)rb;
    }
    if (lane == 0) {
        pos[row] = dot / ((na * nb) / 256.0f) / 256.0f;  // == dot/(na*nb), fp32 exact
        denom[row] = 0.0f;
        denom[row + N_BATCH] = 0.0f;
    }
}

// ---- kernel 2: fused sim = Z Z^T -> exp -> masked row/col sums -----------
// Round-8 fp8 skeleton (3-ring, counted vmcnt(4), bare s_barrier, BK=64,
// triangular grid + bijective XCD swizzle) + PARITY XOR SWIZZLE to kill the
// 4-way ds_read_b64 bank conflict (25.6M extra cycles in round 8):
//   slot s (8B granule of the 32B kh-plane row) holds global octet s ^ v,
//   v = 2*((row>>2)&1). Bank of lane (quad,l15): (l15&3)*8 + s*2 with
//   s = quad ^ 2*((l15>>2)&1) -> each 4-lane group splits 2+2 -> 2-way
//   residual (free, m136). v is EVEN -> each 16B staging chunk maps to a
//   contiguous order-preserving global 16B: src half = (t&1)^((t>>3)&1).
// vmcnt ledger unchanged: 4 loads/thread/step; stage kt+2 during kt;
// boundary vmcnt(4); vmcnt(0) only at tail.
__global__ __launch_bounds__(256, 3) void simexp_kernel(
    const uint8_t* __restrict__ Z, float* __restrict__ denom)
{
    // XCD swizzle then decode linear idx -> (by, bx) with bx >= by
    int orig = blockIdx.x;
    int idx  = (orig & 7) * (NTRI / 8) + (orig >> 3);
    int by = (int)((129.0f - sqrtf(16641.0f - 8.0f * (float)idx)) * 0.5f);
    if (by > NB - 1) by = NB - 1;
    if (by < 0) by = 0;
    int off = (by * (129 - by)) >> 1;           // tiles before row `by`
    while (off > idx)                 { --by; off = (by * (129 - by)) >> 1; }
    while (off + (NB - by) <= idx)    { off += NB - by; ++by; }
    int bx = by + (idx - off);

    int tile_m = by * 128, tile_n = bx * 128;

    // ring: [3][kh 0/1][128 rows * 32 B] per operand -> 24 KiB + 24 KiB
    __shared__ __align__(16) uint8_t shA[3][2 * 4096];
    __shared__ __align__(16) uint8_t shB[3][2 * 4096];

    int t    = threadIdx.x;
    int wv   = t >> 6;
    int lane = t & 63;
    int wave_m = (wv >> 1) * 64;
    int wave_n = (wv & 1) * 64;
    int quad = lane >> 4;
    int l15  = lane & 15;

    // staging: thread t covers (row = t>>1, 16B-half = t&1); LDS dest t*16 is
    // linear; global src 16B-half pre-swizzled: (t&1) ^ ((t>>3)&1)  (v even
    // -> contiguous & order-preserving). kh plane adds kh*32 to the source.
    int shalf = ((t & 1) ^ ((t >> 3) & 1)) * 16;
    const uint8_t* gA = Z + (size_t)(tile_m + (t >> 1)) * D_DIM + shalf;
    const uint8_t* gB = Z + (size_t)(tile_n + (t >> 1)) * D_DIM + shalf;

    // ds_read swizzled slot: s = quad ^ 2*((row>>2)&1); (row>>2)&1 ==
    // (l15>>2)&1 since wave_m and f*16 are multiples of 16.
    int swz = (quad ^ (((l15 >> 2) & 1) << 1)) * 8;

    f32x4 acc[4][4] = {};

    // prologue: stage K-steps 0 and 1 (8 loads/thread); step 0 landed
    #pragma unroll
    for (int pt = 0; pt < 2; ++pt) {
        #pragma unroll
        for (int kh = 0; kh < 2; ++kh) {
            load_lds16(gA + pt * 64 + kh * 32, &shA[pt][kh * 4096 + t * 16]);
            load_lds16(gB + pt * 64 + kh * 32, &shB[pt][kh * 4096 + t * 16]);
        }
    }
    asm volatile("s_waitcnt vmcnt(4)" ::: "memory");
    __builtin_amdgcn_sched_barrier(0);
    __builtin_amdgcn_s_barrier();

    int cur = 0;
    for (int kt = 0; kt < NKT2; ++kt) {
        int wrt = cur + 2; if (wrt >= 3) wrt -= 3;
        if (kt < NKT2 - 2) {             // stage K-step kt+2 into ring slot
            int k0 = (kt + 2) * 64;
            load_lds16(gA + k0,      &shA[wrt][t * 16]);
            load_lds16(gA + k0 + 32, &shA[wrt][4096 + t * 16]);
            load_lds16(gB + k0,      &shB[wrt][t * 16]);
            load_lds16(gB + k0 + 32, &shB[wrt][4096 + t * 16]);
        }
        const uint8_t* sA = shA[cur];
        const uint8_t* sB = shB[cur];
        #pragma unroll
        for (int kh = 0; kh < 2; ++kh) {
            long av[4], bv[4];
            #pragma unroll
            for (int f = 0; f < 4; ++f)
                av[f] = *(const long*)&sA[kh * 4096 + (wave_m + f * 16 + l15) * 32 + swz];
            #pragma unroll
            for (int n = 0; n < 4; ++n)
                bv[n] = *(const long*)&sB[kh * 4096 + (wave_n + n * 16 + l15) * 32 + swz];
            __builtin_amdgcn_s_setprio(1);
            #pragma unroll
            for (int fm = 0; fm < 4; ++fm)
                #pragma unroll
                for (int fn = 0; fn < 4; ++fn)
                    acc[fm][fn] = __builtin_amdgcn_mfma_f32_16x16x32_fp8_fp8(
                        av[fm], bv[fn], acc[fm][fn], 0, 0, 0);
            __builtin_amdgcn_s_setprio(0);
        }
        // boundary: kt+1 must be landed; kt+2's 4 loads may stay in flight
        if (kt < NKT2 - 2) asm volatile("s_waitcnt vmcnt(4)" ::: "memory");
        else               asm volatile("s_waitcnt vmcnt(0)" ::: "memory");
        __builtin_amdgcn_sched_barrier(0);
        __builtin_amdgcn_s_barrier();
        cur = (cur == 2) ? 0 : cur + 1;
    }

    // epilogue: e = exp2(acc * log2(e)/(256 t)) only where c>r; row/col sums
    int rbase = tile_m + wave_m + quad * 4;
    int cbase = tile_n + wave_n + l15;
    float colacc[4] = {0.f, 0.f, 0.f, 0.f};
    #pragma unroll
    for (int fm = 0; fm < 4; ++fm) {
        #pragma unroll
        for (int r = 0; r < 4; ++r) {
            int rg = rbase + fm * 16 + r;
            float rowacc = 0.f;
            #pragma unroll
            for (int fn = 0; fn < 4; ++fn) {
                int cg = cbase + fn * 16;
                float e = (cg > rg)
                    ? __builtin_amdgcn_exp2f(acc[fm][fn][r] * EXP_SCALE_Q)
                    : 0.f;
                rowacc += e;
                colacc[fn] += e;
            }
            rowacc += __shfl_xor(rowacc, 1, 64);
            rowacc += __shfl_xor(rowacc, 2, 64);
            rowacc += __shfl_xor(rowacc, 4, 64);
            rowacc += __shfl_xor(rowacc, 8, 64);
            if (l15 == 0) atomicAdd(&denom[rg], rowacc);
        }
    }
    #pragma unroll
    for (int fn = 0; fn < 4; ++fn) {
        float s = colacc[fn];
        s += __shfl_xor(s, 16, 64);
        s += __shfl_xor(s, 32, 64);
        if (quad == 0) atomicAdd(&denom[cbase + fn * 16], s);
    }
}

// ---- kernel 3: loss = [sum log(denom) - (2/t) sum pos] / 2N --------------
__global__ __launch_bounds__(1024) void finalize_kernel(
    const float* __restrict__ denom, const float* __restrict__ pos,
    float* __restrict__ out)
{
    float a1 = 0.f, a2 = 0.f;
    for (int r = threadIdx.x; r < M_ROWS; r += 1024)
        a1 += __builtin_amdgcn_logf(denom[r]) * LN2;   // v_log_f32 is log2
    for (int i = threadIdx.x; i < N_BATCH; i += 1024)
        a2 += pos[i];
    #pragma unroll
    for (int m = 1; m < 64; m <<= 1) {
        a1 += __shfl_xor(a1, m, 64);
        a2 += __shfl_xor(a2, m, 64);
    }
    __shared__ float r1[16], r2[16];
    int wv = threadIdx.x >> 6;
    if ((threadIdx.x & 63) == 0) { r1[wv] = a1; r2[wv] = a2; }
    __syncthreads();
    if (threadIdx.x == 0) {
        float s1 = 0.f, s2 = 0.f;
        #pragma unroll
        for (int w = 0; w < 16; ++w) { s1 += r1[w]; s2 += r2[w]; }
        out[0] = (s1 - 2.0f * TINV * s2) / (float)M_ROWS;
    }
}

extern "C" void kernel_launch(void* const* d_in, const int* in_sizes, int n_in,
                              void* d_out, int out_size, void* d_ws, size_t ws_size,
                              hipStream_t stream)
{
    const float* emb_i = (const float*)d_in[0];
    const float* emb_j = (const float*)d_in[1];
    float* out = (float*)d_out;

    char*    ws    = (char*)d_ws;
    uint8_t* z8    = (uint8_t*)ws;                                 // 8 MB
    float*   denom = (float*)(ws + (size_t)M_ROWS * D_DIM);        // 32 KB
    float*   pos   = denom + M_ROWS;                               // 16 KB

    hipLaunchKernelGGL(norm_pos_kernel, dim3(N_BATCH / 4), dim3(256), 0, stream,
                       emb_i, emb_j, z8, pos, denom);
    hipLaunchKernelGGL(simexp_kernel, dim3(NTRI), dim3(256), 0, stream,
                       z8, denom);
    hipLaunchKernelGGL(finalize_kernel, dim3(1), dim3(1024), 0, stream,
                       denom, pos, out);
}

// Round 10
// 163.547 us; speedup vs baseline: 1.1320x; 1.0249x over previous
//
#include <hip/hip_runtime.h>
#include <hip/hip_bf16.h>
#include <stdint.h>

#define N_BATCH 4096
#define D_DIM   1024
#define M_ROWS  8192                     // 2N
#define TINV    2.0f                     // 1/temperature
// acc = sum q(16 z_r) q(16 z_c) = 256*sim ; exp2(acc * log2(e)/(256 t))
#define EXP_SCALE_Q (2.8853900817779268f / 256.0f)
#define LN2 0.6931471805599453f
#define NB 64                            // 8192/128 tiles per dim
#define NTRI 2080                        // NB*(NB+1)/2 upper-tri tiles
#define NKT2 16                          // K steps of 64 (K=1024)

typedef float f32x4 __attribute__((ext_vector_type(4)));

// ---- kernel 1: fused L2-normalize (fp8 e4m3 Z out, x16 scale) + positives --
// One wave per row-pair; wave-local shfl reduce; no LDS/syncthreads.
__global__ __launch_bounds__(256) void norm_pos_kernel(
    const float* __restrict__ emb_i, const float* __restrict__ emb_j,
    uint8_t* __restrict__ z8, float* __restrict__ pos, float* __restrict__ denom)
{
    int w    = threadIdx.x >> 6;                 // wave 0..3
    int lane = threadIdx.x & 63;
    int row  = blockIdx.x * 4 + w;               // 0..4095 (grid = 1024)
    const float4* Ai = (const float4*)(emb_i + (size_t)row * D_DIM);
    const float4* Bj = (const float4*)(emb_j + (size_t)row * D_DIM);
    float4 a[4], b[4];
    #pragma unroll
    for (int j = 0; j < 4; ++j) {
        a[j] = Ai[lane + 64 * j];
        b[j] = Bj[lane + 64 * j];
    }
    float ssa = 0.f, ssb = 0.f, dot = 0.f;
    #pragma unroll
    for (int j = 0; j < 4; ++j) {
        ssa += a[j].x*a[j].x + a[j].y*a[j].y + a[j].z*a[j].z + a[j].w*a[j].w;
        ssb += b[j].x*b[j].x + b[j].y*b[j].y + b[j].z*b[j].z + b[j].w*b[j].w;
        dot += a[j].x*b[j].x + a[j].y*b[j].y + a[j].z*b[j].z + a[j].w*b[j].w;
    }
    #pragma unroll
    for (int m = 1; m < 64; m <<= 1) {
        ssa += __shfl_xor(ssa, m, 64);
        ssb += __shfl_xor(ssb, m, 64);
        dot += __shfl_xor(dot, m, 64);
    }
    float na = fmaxf(sqrtf(ssa), 1e-12f);
    float nb = fmaxf(sqrtf(ssb), 1e-12f);
    float sa = 16.0f / na, sb = 16.0f / nb;
    uint32_t* zr = (uint32_t*)(z8 + (size_t)row * D_DIM);
    uint32_t* zc = (uint32_t*)(z8 + (size_t)(row + N_BATCH) * D_DIM);
    #pragma unroll
    for (int j = 0; j < 4; ++j) {
        int ra = 0, rb = 0;
        ra = __builtin_amdgcn_cvt_pk_fp8_f32(a[j].x * sa, a[j].y * sa, ra, false);
        ra = __builtin_amdgcn_cvt_pk_fp8_f32(a[j].z * sa, a[j].w * sa, ra, true);
        rb = __builtin_amdgcn_cvt_pk_fp8_f32(b[j].x * sb, b[j].y * sb, rb, false);
        rb = __builtin_amdgcn_cvt_pk_fp8_f32(b[j].z * sb, b[j].w * sb, rb, true);
        zr[lane + 64 * j] = (uint32_t)ra;
        zc[lane + 64 * j] = (uint32_t)rb;
    }
    if (lane == 0) {
        pos[row] = dot / ((na * nb) / 256.0f) / 256.0f;  // == dot/(na*nb)
        denom[row] = 0.0f;
        denom[row + N_BATCH] = 0.0f;
    }
}

// ---- kernel 2: fused sim = Z Z^T -> exp -> masked row/col sums -----------
// fp8 BK=64 skeleton (3-ring 48KiB -> 3 blk/CU, counted waits, bare
// s_barrier, triangular grid + bijective XCD swizzle) with REG-STAGING
// (T14) replacing global_load_lds, enabling an octet-granular LDS layout
// that is conflict-free on BOTH sides (round-9 residual was a structural
// 2x: 16B DMA chunks force lane-uniform slot parity -> <=16 banks per
// quarter-wave in any chunk layout):
//   layout: [kh][o][row'] with row' = (row + o*4) & 127, 8B per entry.
//   reads  (fixed kh,o=quad per instr): banks = (row+quad*4)*2 over 16
//          consecutive rows -> all 32 banks, conflict-free.
//   writes (o = 2*(t&1)+{0,1} per instr): rows 0..7 x o-parity split ->
//          all 32 banks, conflict-free (derived per-lane).
// T14 schedule per step kt: issue 4 global_load_dwordx4 (tile kt+2) at the
// TOP; ds_read+MFMA on tile kt covers their ~600cy latency; then own-load
// vmcnt(0) + 8 ds_write_b64 + lgkmcnt(0) + s_barrier. Ring distance 2 as
// before (writers of slot (kt+2)%3 vs readers done at kt-1).
__global__ __launch_bounds__(256, 3) void simexp_kernel(
    const uint8_t* __restrict__ Z, float* __restrict__ denom)
{
    // XCD swizzle then decode linear idx -> (by, bx) with bx >= by
    int orig = blockIdx.x;
    int idx  = (orig & 7) * (NTRI / 8) + (orig >> 3);
    int by = (int)((129.0f - sqrtf(16641.0f - 8.0f * (float)idx)) * 0.5f);
    if (by > NB - 1) by = NB - 1;
    if (by < 0) by = 0;
    int off = (by * (129 - by)) >> 1;           // tiles before row `by`
    while (off > idx)                 { --by; off = (by * (129 - by)) >> 1; }
    while (off + (NB - by) <= idx)    { off += NB - by; ++by; }
    int bx = by + (idx - off);

    int tile_m = by * 128, tile_n = bx * 128;

    // ring: [3][kh 0/1][o 0..3][row' 0..127][8B] per operand = 8KB/slot
    __shared__ __align__(16) uint8_t shA[3][8192];
    __shared__ __align__(16) uint8_t shB[3][8192];

    int t    = threadIdx.x;
    int lane = t & 63;
    int wv   = t >> 6;
    int wave_m = (wv >> 1) * 64;
    int wave_n = (wv & 1) * 64;
    int quad = lane >> 4;
    int l15  = lane & 15;

    // staging: thread t owns (row = t>>1, 16B-half = t&1) of each kh plane
    int srow = t >> 1;
    int oL   = (t & 1) * 2;                      // chunk = octets oL, oL+1
    const uint8_t* gA = Z + (size_t)(tile_m + srow) * D_DIM + (t & 1) * 16;
    const uint8_t* gB = Z + (size_t)(tile_n + srow) * D_DIM + (t & 1) * 16;

    // write offsets (per kh plane, per octet): o*1024 + ((row+o*4)&127)*8
    int woffL = oL * 1024       + (((srow + oL * 4)     & 127) << 3);
    int woffH = (oL + 1) * 1024 + (((srow + oL * 4 + 4) & 127) << 3);

    // read row-rotation base: row' = (wavebase + f*16 + l15 + quad*4)&127
    int rrA = wave_m + l15 + quad * 4;
    int rrB = wave_n + l15 + quad * 4;
    int rquad = quad * 1024;

    f32x4 acc[4][4] = {};
    union LD { int4 v; long l[2]; };

    // prologue: stage K-steps 0 and 1 via reg-staging
    #pragma unroll
    for (int pt = 0; pt < 2; ++pt) {
        LD a0, a1, b0, b1;
        int k0 = pt * 64;
        a0.v = *(const int4*)(gA + k0);
        a1.v = *(const int4*)(gA + k0 + 32);
        b0.v = *(const int4*)(gB + k0);
        b1.v = *(const int4*)(gB + k0 + 32);
        asm volatile("s_waitcnt vmcnt(0)" ::: "memory");
        __builtin_amdgcn_sched_barrier(0);
        *(long*)&shA[pt][woffL]        = a0.l[0];
        *(long*)&shA[pt][woffH]        = a0.l[1];
        *(long*)&shA[pt][4096 + woffL] = a1.l[0];
        *(long*)&shA[pt][4096 + woffH] = a1.l[1];
        *(long*)&shB[pt][woffL]        = b0.l[0];
        *(long*)&shB[pt][woffH]        = b0.l[1];
        *(long*)&shB[pt][4096 + woffL] = b1.l[0];
        *(long*)&shB[pt][4096 + woffH] = b1.l[1];
    }
    asm volatile("s_waitcnt lgkmcnt(0)" ::: "memory");
    __builtin_amdgcn_sched_barrier(0);
    __builtin_amdgcn_s_barrier();

    int cur = 0;
    for (int kt = 0; kt < NKT2; ++kt) {
        int wrt = cur + 2; if (wrt >= 3) wrt -= 3;
        bool stg = (kt < NKT2 - 2);
        LD a0, a1, b0, b1;
        if (stg) {                       // issue tile kt+2 loads EARLY (T14)
            int k0 = (kt + 2) * 64;
            a0.v = *(const int4*)(gA + k0);
            a1.v = *(const int4*)(gA + k0 + 32);
            b0.v = *(const int4*)(gB + k0);
            b1.v = *(const int4*)(gB + k0 + 32);
        }
        const uint8_t* sA = shA[cur];
        const uint8_t* sB = shB[cur];
        #pragma unroll
        for (int kh = 0; kh < 2; ++kh) {
            long av[4], bv[4];
            #pragma unroll
            for (int f = 0; f < 4; ++f)
                av[f] = *(const long*)&sA[kh * 4096 + rquad
                         + ((((rrA + f * 16)) & 127) << 3)];
            #pragma unroll
            for (int n = 0; n < 4; ++n)
                bv[n] = *(const long*)&sB[kh * 4096 + rquad
                         + ((((rrB + n * 16)) & 127) << 3)];
            __builtin_amdgcn_s_setprio(1);
            #pragma unroll
            for (int fm = 0; fm < 4; ++fm)
                #pragma unroll
                for (int fn = 0; fn < 4; ++fn)
                    acc[fm][fn] = __builtin_amdgcn_mfma_f32_16x16x32_fp8_fp8(
                        av[fm], bv[fn], acc[fm][fn], 0, 0, 0);
            __builtin_amdgcn_s_setprio(0);
        }
        if (stg) {                       // own loads landed under the MFMAs
            asm volatile("s_waitcnt vmcnt(0)" ::: "memory");
            __builtin_amdgcn_sched_barrier(0);
            *(long*)&shA[wrt][woffL]        = a0.l[0];
            *(long*)&shA[wrt][woffH]        = a0.l[1];
            *(long*)&shA[wrt][4096 + woffL] = a1.l[0];
            *(long*)&shA[wrt][4096 + woffH] = a1.l[1];
            *(long*)&shB[wrt][woffL]        = b0.l[0];
            *(long*)&shB[wrt][woffH]        = b0.l[1];
            *(long*)&shB[wrt][4096 + woffL] = b1.l[0];
            *(long*)&shB[wrt][4096 + woffH] = b1.l[1];
        }
        asm volatile("s_waitcnt lgkmcnt(0)" ::: "memory");
        __builtin_amdgcn_sched_barrier(0);
        __builtin_amdgcn_s_barrier();
        cur = (cur == 2) ? 0 : cur + 1;
    }

    // epilogue: e = exp2(acc * log2(e)/(256 t)) only where c>r; row/col sums
    int rbase = tile_m + wave_m + quad * 4;
    int cbase = tile_n + wave_n + l15;
    float colacc[4] = {0.f, 0.f, 0.f, 0.f};
    #pragma unroll
    for (int fm = 0; fm < 4; ++fm) {
        #pragma unroll
        for (int r = 0; r < 4; ++r) {
            int rg = rbase + fm * 16 + r;
            float rowacc = 0.f;
            #pragma unroll
            for (int fn = 0; fn < 4; ++fn) {
                int cg = cbase + fn * 16;
                float e = (cg > rg)
                    ? __builtin_amdgcn_exp2f(acc[fm][fn][r] * EXP_SCALE_Q)
                    : 0.f;
                rowacc += e;
                colacc[fn] += e;
            }
            rowacc += __shfl_xor(rowacc, 1, 64);
            rowacc += __shfl_xor(rowacc, 2, 64);
            rowacc += __shfl_xor(rowacc, 4, 64);
            rowacc += __shfl_xor(rowacc, 8, 64);
            if (l15 == 0) atomicAdd(&denom[rg], rowacc);
        }
    }
    #pragma unroll
    for (int fn = 0; fn < 4; ++fn) {
        float s = colacc[fn];
        s += __shfl_xor(s, 16, 64);
        s += __shfl_xor(s, 32, 64);
        if (quad == 0) atomicAdd(&denom[cbase + fn * 16], s);
    }
}

// ---- kernel 3: loss = [sum log(denom) - (2/t) sum pos] / 2N --------------
__global__ __launch_bounds__(1024) void finalize_kernel(
    const float* __restrict__ denom, const float* __restrict__ pos,
    float* __restrict__ out)
{
    float a1 = 0.f, a2 = 0.f;
    for (int r = threadIdx.x; r < M_ROWS; r += 1024)
        a1 += __builtin_amdgcn_logf(denom[r]) * LN2;   // v_log_f32 is log2
    for (int i = threadIdx.x; i < N_BATCH; i += 1024)
        a2 += pos[i];
    #pragma unroll
    for (int m = 1; m < 64; m <<= 1) {
        a1 += __shfl_xor(a1, m, 64);
        a2 += __shfl_xor(a2, m, 64);
    }
    __shared__ float r1[16], r2[16];
    int wv = threadIdx.x >> 6;
    if ((threadIdx.x & 63) == 0) { r1[wv] = a1; r2[wv] = a2; }
    __syncthreads();
    if (threadIdx.x == 0) {
        float s1 = 0.f, s2 = 0.f;
        #pragma unroll
        for (int w = 0; w < 16; ++w) { s1 += r1[w]; s2 += r2[w]; }
        out[0] = (s1 - 2.0f * TINV * s2) / (float)M_ROWS;
    }
}

extern "C" void kernel_launch(void* const* d_in, const int* in_sizes, int n_in,
                              void* d_out, int out_size, void* d_ws, size_t ws_size,
                              hipStream_t stream)
{
    const float* emb_i = (const float*)d_in[0];
    const float* emb_j = (const float*)d_in[1];
    float* out = (float*)d_out;

    char*    ws    = (char*)d_ws;
    uint8_t* z8    = (uint8_t*)ws;                                 // 8 MB
    float*   denom = (float*)(ws + (size_t)M_ROWS * D_DIM);        // 32 KB
    float*   pos   = denom + M_ROWS;                               // 16 KB

    hipLaunchKernelGGL(norm_pos_kernel, dim3(N_BATCH / 4), dim3(256), 0, stream,
                       emb_i, emb_j, z8, pos, denom);
    hipLaunchKernelGGL(simexp_kernel, dim3(NTRI), dim3(256), 0, stream,
                       z8, denom);
    hipLaunchKernelGGL(finalize_kernel, dim3(1), dim3(1024), 0, stream,
                       denom, pos, out);
}